// Round 1
// baseline (566.429 us; speedup 1.0000x reference)
//
#include <hip/hip_runtime.h>
#include <math.h>

#define B_ 8
#define H_ 128
#define L_ 16384
#define N_ 16
#define CHUNK_ 64
#define NCH_ 256   // L_ / CHUNK_

// ---------------------------------------------------------------------------
// prep: per-(h,n) SSM constants, transposed weights, FiLM gains, zero BN sums
// ---------------------------------------------------------------------------
__global__ __launch_bounds__(256) void prep_kernel(
    const float* __restrict__ lin_w, const float* __restrict__ out_w,
    const float* __restrict__ log_dt, const float* __restrict__ log_A_real,
    const float* __restrict__ A_imag, const float* __restrict__ C_re,
    const float* __restrict__ C_im, const float* __restrict__ cond,
    const float* __restrict__ film_w, const float* __restrict__ film_b,
    float* __restrict__ wtA, float* __restrict__ wtB, float* __restrict__ consts,
    float* __restrict__ gact, float* __restrict__ bact,
    double* __restrict__ bnsum, double* __restrict__ bnsumsq)
{
  int t = threadIdx.x;
  // transposed weights: wt[h][g] = w[g][h]  (coalesced LDS staging later)
  for (int i = t; i < H_ * H_; i += 256) {
    int h = i >> 7, g = i & 127;
    wtA[i] = lin_w[g * H_ + h];
    wtB[i] = out_w[g * H_ + h];
  }
  // SSM constants per (h, n)
  for (int i = t; i < H_ * N_; i += 256) {
    int h = i >> 4, n = i & 15;
    float dt  = expf(log_dt[h]);
    float Are = -expf(log_A_real[i]);
    float Aim = A_imag[i];
    float dre = dt * Are, dim = dt * Aim;
    float er  = expf(dre);
    float wre = er * cosf(dim);
    float wim = er * sinf(dim);
    float den = Are * Are + Aim * Aim;
    float nre = wre - 1.0f, nim = wim;
    float dBre = (nre * Are + nim * Aim) / den;
    float dBim = (nim * Are - nre * Aim) / den;
    float cr = C_re[i], ci = C_im[i];
    float cere = cr * dBre - ci * dBim;
    float ceim = cr * dBim + ci * dBre;
    float e2   = expf((float)CHUNK_ * dre);
    float wcre = e2 * cosf((float)CHUNK_ * dim);
    float wcim = e2 * sinf((float)CHUNK_ * dim);
    float* cb = consts + h * 96;
    cb[n]      = wre;  cb[16 + n] = wim;
    cb[32 + n] = cere; cb[48 + n] = ceim;
    cb[64 + n] = wcre; cb[80 + n] = wcim;
  }
  // FiLM: gb[b][k] = sum_c cond[b][c]*film_w[k][c] + film_b[k]
  for (int i = t; i < B_ * 2 * H_; i += 256) {
    int b = i >> 8, k = i & 255;
    float acc = film_b[k];
    #pragma unroll
    for (int c = 0; c < 4; c++) acc += cond[b * 4 + c] * film_w[k * 4 + c];
    if (k < H_) gact[b * H_ + k] = acc;
    else        bact[b * H_ + (k - H_)] = acc;
  }
  if (t < H_) { bnsum[t] = 0.0; bnsumsq[t] = 0.0; }
}

// ---------------------------------------------------------------------------
// GEMM: out[b,g,j] = sum_h wt[h][g] * in[b,h,j] (+bias, +prelu / +BN stats)
// block = 256 threads, tile 128g x 128j, 8x8 micro-tile, K staged in 16-h LDS
// MODE 0: lin + prelu.  MODE 1: out layer + bias + BN partial sums (in-place ok)
// ---------------------------------------------------------------------------
template<int MODE>
__global__ __launch_bounds__(256) void gemm_kernel(
    const float* in, const float* __restrict__ wt,
    const float* __restrict__ bias, const float* __restrict__ prelu_a,
    float* out, double* __restrict__ bnsum, double* __restrict__ bnsumsq)
{
  __shared__ __align__(16) float wsh[16][128];
  __shared__ __align__(16) float xsh[16][128];
  int tid = threadIdx.x;
  int b  = blockIdx.x >> 7;
  int j0 = (blockIdx.x & 127) << 7;
  const float* inb = in + ((size_t)b * H_) * L_ + j0;
  int tg = tid >> 4, tj = tid & 15;
  float acc[8][8];
  #pragma unroll
  for (int a = 0; a < 8; a++)
    #pragma unroll
    for (int c = 0; c < 8; c++) acc[a][c] = 0.0f;

  for (int h0 = 0; h0 < H_; h0 += 16) {
    #pragma unroll
    for (int i = 0; i < 2; i++) {
      int f4 = tid + i * 256;           // 0..511
      int hh = f4 >> 5, q = f4 & 31;
      *reinterpret_cast<float4*>(&wsh[hh][q * 4]) =
          *reinterpret_cast<const float4*>(&wt[(h0 + hh) * H_ + q * 4]);
      *reinterpret_cast<float4*>(&xsh[hh][q * 4]) =
          *reinterpret_cast<const float4*>(&inb[(size_t)(h0 + hh) * L_ + q * 4]);
    }
    __syncthreads();
    #pragma unroll
    for (int hh = 0; hh < 16; hh++) {
      float4 w0 = *reinterpret_cast<float4*>(&wsh[hh][tg * 8]);
      float4 w1 = *reinterpret_cast<float4*>(&wsh[hh][tg * 8 + 4]);
      float4 x0 = *reinterpret_cast<float4*>(&xsh[hh][tj * 8]);
      float4 x1 = *reinterpret_cast<float4*>(&xsh[hh][tj * 8 + 4]);
      float wv[8] = {w0.x, w0.y, w0.z, w0.w, w1.x, w1.y, w1.z, w1.w};
      float xv[8] = {x0.x, x0.y, x0.z, x0.w, x1.x, x1.y, x1.z, x1.w};
      #pragma unroll
      for (int a = 0; a < 8; a++)
        #pragma unroll
        for (int c = 0; c < 8; c++)
          acc[a][c] = fmaf(wv[a], xv[c], acc[a][c]);
    }
    __syncthreads();
  }

  float pa = 0.0f;
  if (MODE == 0) pa = prelu_a[0];
  #pragma unroll
  for (int a = 0; a < 8; a++) {
    int g = tg * 8 + a;
    float bv = bias[g];
    float vals[8];
    #pragma unroll
    for (int c = 0; c < 8; c++) {
      float v = acc[a][c] + bv;
      if (MODE == 0) v = (v > 0.0f) ? v : pa * v;
      vals[c] = v;
    }
    float* op = out + ((size_t)b * H_ + g) * L_ + j0 + tj * 8;
    *reinterpret_cast<float4*>(op)     = make_float4(vals[0], vals[1], vals[2], vals[3]);
    *reinterpret_cast<float4*>(op + 4) = make_float4(vals[4], vals[5], vals[6], vals[7]);
    if (MODE == 1) {
      float s = 0.0f, s2 = 0.0f;
      #pragma unroll
      for (int c = 0; c < 8; c++) { s += vals[c]; s2 = fmaf(vals[c], vals[c], s2); }
      #pragma unroll
      for (int off = 1; off < 16; off <<= 1) {
        s  += __shfl_xor(s, off);
        s2 += __shfl_xor(s2, off);
      }
      if (tj == 0) {
        atomicAdd(&bnsum[g], (double)s);
        atomicAdd(&bnsumsq[g], (double)s2);
      }
    }
  }
}

// ---------------------------------------------------------------------------
// Chunked SSM scan, in-place u -> y.  One block per (b,h) row; lane = chunk
// of 64 elems; 16 complex modes per lane.  phase1 local states -> LDS ->
// serial cross-chunk combine (per n) -> phase2 re-scan producing y.
// ---------------------------------------------------------------------------
__global__ __launch_bounds__(256) void scan_kernel(
    float* u, const float* __restrict__ consts, const float* __restrict__ Dp)
{
  __shared__ float slds[NCH_][34];     // [chunk][2n + pad] (pad -> ~2-way banks)
  int c   = threadIdx.x;               // chunk id 0..255
  int row = blockIdx.x;                // b*H + h
  int h   = row & 127;
  const float* cb = consts + h * 96;   // uniform -> s_loads
  float wre[16], wim[16];
  #pragma unroll
  for (int n = 0; n < 16; n++) { wre[n] = cb[n]; wim[n] = cb[16 + n]; }

  float* up = u + ((size_t)row << 14) + c * CHUNK_;
  float sre[16], sim[16];
  #pragma unroll
  for (int n = 0; n < 16; n++) { sre[n] = 0.0f; sim[n] = 0.0f; }

  // phase 1: local chunk states
  float4 uv = *reinterpret_cast<float4*>(&up[0]);
  for (int q = 0; q < 16; q++) {
    float4 nxt = uv;
    if (q < 15) nxt = *reinterpret_cast<float4*>(&up[(q + 1) * 4]);
    float uu[4] = {uv.x, uv.y, uv.z, uv.w};
    #pragma unroll
    for (int k = 0; k < 4; k++) {
      float uval = uu[k];
      #pragma unroll
      for (int n = 0; n < 16; n++) {
        float nr = fmaf(wre[n], sre[n], fmaf(-wim[n], sim[n], uval));
        float ni = fmaf(wre[n], sim[n], wim[n] * sre[n]);
        sre[n] = nr; sim[n] = ni;
      }
    }
    uv = nxt;
  }
  #pragma unroll
  for (int n = 0; n < 16; n++) { slds[c][2 * n] = sre[n]; slds[c][2 * n + 1] = sim[n]; }
  __syncthreads();

  // cross-chunk combine (serial per mode): replace Sloc with incoming state
  if (c < 16) {
    int n = c;
    float wcr = cb[64 + n], wci = cb[80 + n];
    float car = 0.0f, cai = 0.0f;
    for (int cc = 0; cc < NCH_; cc++) {
      float lr = slds[cc][2 * n], li = slds[cc][2 * n + 1];
      slds[cc][2 * n] = car; slds[cc][2 * n + 1] = cai;
      float nr = fmaf(wcr, car, fmaf(-wci, cai, lr));
      float ni = fmaf(wcr, cai, fmaf(wci, car, li));
      car = nr; cai = ni;
    }
  }
  __syncthreads();

  // phase 2: seeded re-scan, emit y = 2*Re(sum Ceff*s) + D*u  (in place)
  float cre[16], cim[16];
  #pragma unroll
  for (int n = 0; n < 16; n++) { cre[n] = cb[32 + n]; cim[n] = cb[48 + n]; }
  float Dv = Dp[h];
  #pragma unroll
  for (int n = 0; n < 16; n++) { sre[n] = slds[c][2 * n]; sim[n] = slds[c][2 * n + 1]; }

  uv = *reinterpret_cast<float4*>(&up[0]);
  for (int q = 0; q < 16; q++) {
    float4 nxt = uv;
    if (q < 15) nxt = *reinterpret_cast<float4*>(&up[(q + 1) * 4]);
    float uu[4] = {uv.x, uv.y, uv.z, uv.w};
    float yy[4];
    #pragma unroll
    for (int k = 0; k < 4; k++) {
      float uval = uu[k];
      float ya = 0.0f;
      #pragma unroll
      for (int n = 0; n < 16; n++) {
        float nr = fmaf(wre[n], sre[n], fmaf(-wim[n], sim[n], uval));
        float ni = fmaf(wre[n], sim[n], wim[n] * sre[n]);
        sre[n] = nr; sim[n] = ni;
        ya = fmaf(cre[n], nr, fmaf(-cim[n], ni, ya));
      }
      yy[k] = fmaf(Dv, uval, 2.0f * ya);
    }
    *reinterpret_cast<float4*>(&up[q * 4]) = make_float4(yy[0], yy[1], yy[2], yy[3]);
    uv = nxt;
  }
}

// ---------------------------------------------------------------------------
__global__ void bnfinal_kernel(const double* __restrict__ bnsum,
                               const double* __restrict__ bnsumsq,
                               float* __restrict__ meanp, float* __restrict__ invp)
{
  int g = threadIdx.x;
  if (g < H_) {
    double cnt = (double)B_ * (double)L_;
    double mu  = bnsum[g] / cnt;
    double var = bnsumsq[g] / cnt - mu * mu;
    meanp[g] = (float)mu;
    invp[g]  = (float)(1.0 / sqrt(var + 1e-5));
  }
}

// ---------------------------------------------------------------------------
// final: BN normalize + FiLM + prelu2 + residual, elementwise, in place
// ---------------------------------------------------------------------------
__global__ __launch_bounds__(256) void final_kernel(
    float* zio, const float* __restrict__ x,
    const float* __restrict__ meanp, const float* __restrict__ invp,
    const float* __restrict__ gact, const float* __restrict__ bact,
    const float* __restrict__ prelu2_a, const float* __restrict__ res_w)
{
  size_t i4 = (size_t)blockIdx.x * 256 + threadIdx.x;
  size_t e  = i4 * 4;
  int bg = (int)(e >> 14);             // e / L_
  int g  = bg & 127;
  float m  = meanp[g], iv = invp[g];
  float ga = gact[bg], bb = bact[bg];
  float rw = res_w[g], pa = prelu2_a[0];
  float4 zv = *reinterpret_cast<float4*>(&zio[e]);
  const float4 xv = *reinterpret_cast<const float4*>(&x[e]);
  float zz[4] = {zv.x, zv.y, zv.z, zv.w};
  float xx[4] = {xv.x, xv.y, xv.z, xv.w};
  #pragma unroll
  for (int k = 0; k < 4; k++) {
    float v = fmaf((zz[k] - m) * iv, ga, bb);
    v = (v > 0.0f) ? v : pa * v;
    zz[k] = fmaf(rw, xx[k], v);
  }
  *reinterpret_cast<float4*>(&zio[e]) = make_float4(zz[0], zz[1], zz[2], zz[3]);
}

// ---------------------------------------------------------------------------
extern "C" void kernel_launch(void* const* d_in, const int* in_sizes, int n_in,
                              void* d_out, int out_size, void* d_ws, size_t ws_size,
                              hipStream_t stream)
{
  const float* x        = (const float*)d_in[0];
  const float* cond     = (const float*)d_in[1];
  const float* lin_w    = (const float*)d_in[2];
  const float* lin_b    = (const float*)d_in[3];
  const float* prelu1_a = (const float*)d_in[4];
  const float* log_dt   = (const float*)d_in[5];
  const float* log_A    = (const float*)d_in[6];
  const float* A_imag   = (const float*)d_in[7];
  const float* C_re     = (const float*)d_in[8];
  const float* C_im     = (const float*)d_in[9];
  const float* Dp       = (const float*)d_in[10];
  const float* out_w    = (const float*)d_in[11];
  const float* out_b    = (const float*)d_in[12];
  const float* film_w   = (const float*)d_in[13];
  const float* film_b   = (const float*)d_in[14];
  const float* prelu2_a = (const float*)d_in[15];
  const float* res_w    = (const float*)d_in[16];
  float* out = (float*)d_out;

  char* wsb = (char*)d_ws;
  double* bnsum   = (double*)(wsb + 0);        // 128 doubles
  double* bnsumsq = (double*)(wsb + 1024);     // 128 doubles
  float* consts   = (float*)(wsb + 2048);      // 128*96 floats
  float* wtA      = (float*)(wsb + 51200);     // 16384 floats
  float* wtB      = (float*)(wsb + 116736);    // 16384 floats
  float* gact     = (float*)(wsb + 182272);    // 1024 floats
  float* bact     = (float*)(wsb + 186368);    // 1024 floats
  float* meanp    = (float*)(wsb + 190464);    // 128 floats
  float* invp     = (float*)(wsb + 190976);    // 128 floats

  prep_kernel<<<1, 256, 0, stream>>>(lin_w, out_w, log_dt, log_A, A_imag, C_re, C_im,
                                     cond, film_w, film_b, wtA, wtB, consts, gact, bact,
                                     bnsum, bnsumsq);
  // lin + prelu: x -> u (in d_out)
  gemm_kernel<0><<<1024, 256, 0, stream>>>(x, wtA, lin_b, prelu1_a, out, nullptr, nullptr);
  // SSM conv + D*u: u -> y, in place
  scan_kernel<<<1024, 256, 0, stream>>>(out, consts, Dp);
  // out layer + bias + BN stats: y -> z, in place
  gemm_kernel<1><<<1024, 256, 0, stream>>>(out, wtB, out_b, nullptr, out, bnsum, bnsumsq);
  bnfinal_kernel<<<1, 128, 0, stream>>>(bnsum, bnsumsq, meanp, invp);
  // BN + FiLM + prelu2 + residual, in place
  final_kernel<<<16384, 256, 0, stream>>>(out, x, meanp, invp, gact, bact, prelu2_a, res_w);
}

// Round 3
// 393.565 us; speedup vs baseline: 1.4392x; 1.4392x over previous
//
#include <hip/hip_runtime.h>
#include <math.h>

#define B_ 8
#define H_ 128
#define L_ 16384
#define N_ 16
#define CHUNK_ 64
#define NCH_ 256   // L_ / CHUNK_
#define NBLK_ 2048 // gemm grid (8 b x 256 j-tiles of 64)

typedef float f32x4 __attribute__((ext_vector_type(4)));
typedef short bf16x8 __attribute__((ext_vector_type(8)));

static __device__ __forceinline__ unsigned int f2bf(float f) {
  unsigned int u = __float_as_uint(f);
  unsigned int r = u + 0x7FFFu + ((u >> 16) & 1u);
  return r >> 16;   // RNE bf16 in low 16 bits
}

// ---------------------------------------------------------------------------
// prep: bf16 weights, per-(h,n) SSM constants, FiLM gains, zero BN sums
// ---------------------------------------------------------------------------
__global__ __launch_bounds__(256) void prep_kernel(
    const float* __restrict__ lin_w, const float* __restrict__ out_w,
    const float* __restrict__ log_dt, const float* __restrict__ log_A_real,
    const float* __restrict__ A_imag, const float* __restrict__ C_re,
    const float* __restrict__ C_im, const float* __restrict__ cond,
    const float* __restrict__ film_w, const float* __restrict__ film_b,
    unsigned short* __restrict__ wA16, unsigned short* __restrict__ wB16,
    float* __restrict__ consts,
    float* __restrict__ gact, float* __restrict__ bact,
    float* __restrict__ bnsum, float* __restrict__ bnsumsq)
{
  int t = threadIdx.x;
  // bf16 weights, layout [g][h] as given (A-operand reads contiguous along h)
  for (int i = t; i < H_ * H_; i += 256) {
    wA16[i] = (unsigned short)f2bf(lin_w[i]);
    wB16[i] = (unsigned short)f2bf(out_w[i]);
  }
  // SSM constants per (h, n)
  for (int i = t; i < H_ * N_; i += 256) {
    int h = i >> 4, n = i & 15;
    float dt  = expf(log_dt[h]);
    float Are = -expf(log_A_real[i]);
    float Aim = A_imag[i];
    float dre = dt * Are, dim = dt * Aim;
    float er  = expf(dre);
    float wre = er * cosf(dim);
    float wim = er * sinf(dim);
    float den = Are * Are + Aim * Aim;
    float nre = wre - 1.0f, nim = wim;
    float dBre = (nre * Are + nim * Aim) / den;
    float dBim = (nim * Are - nre * Aim) / den;
    float cr = C_re[i], ci = C_im[i];
    float cere = cr * dBre - ci * dBim;
    float ceim = cr * dBim + ci * dBre;
    float e2   = expf((float)CHUNK_ * dre);
    float wcre = e2 * cosf((float)CHUNK_ * dim);
    float wcim = e2 * sinf((float)CHUNK_ * dim);
    float* cb = consts + h * 96;
    cb[n]      = wre;  cb[16 + n] = wim;
    cb[32 + n] = cere; cb[48 + n] = ceim;
    cb[64 + n] = wcre; cb[80 + n] = wcim;
  }
  // FiLM: gb[b][k] = sum_c cond[b][c]*film_w[k][c] + film_b[k]
  for (int i = t; i < B_ * 2 * H_; i += 256) {
    int b = i >> 8, k = i & 255;
    float acc = film_b[k];
    #pragma unroll
    for (int c = 0; c < 4; c++) acc += cond[b * 4 + c] * film_w[k * 4 + c];
    if (k < H_) gact[b * H_ + k] = acc;
    else        bact[b * H_ + (k - H_)] = acc;
  }
  if (t < H_) { bnsum[t] = 0.0f; bnsumsq[t] = 0.0f; }
}

// ---------------------------------------------------------------------------
// MFMA GEMM: out[b,g,j] = sum_h W[g][h] * in[b,h,j] (+bias; prelu or BN stats)
// block = 256 thr (4 waves), tile 128g x 64j, K=128 in one LDS-staged shot.
// A-frags straight from global bf16 W (L2-hot).  B-frags from swizzled LDS
// x^T tile (f32 global -> bf16 regs -> LDS transpose during staging).
// MODE 0: +lin_b, prelu.  MODE 1: +out_b, BN sums via LDS + 1 f32 atomic/g.
// In-place safe: block reads all h rows of cols [jb,jb+64) before any store,
// and writes exactly those (g, j) cols.
// ---------------------------------------------------------------------------
template<int MODE>
__global__ __launch_bounds__(256) void mgemm_kernel(
    const float* in, const unsigned short* __restrict__ w16,
    const float* __restrict__ bias, const float* __restrict__ prelu_a,
    float* out, float* __restrict__ bnsum, float* __restrict__ bnsumsq)
{
  __shared__ __align__(16) unsigned short xT[64 * 128];  // swizzled [j][h]
  __shared__ float bs1[128], bs2[128];
  char* xb = (char*)xT;
  int tid = threadIdx.x;
  int blk = blockIdx.x;
  int b   = blk >> 8;
  int jb  = (blk & 255) << 6;
  const float* inb = in + ((size_t)b * H_) * L_ + jb;

  if (MODE == 1 && tid < 128) { bs1[tid] = 0.0f; bs2[tid] = 0.0f; }

  // ---- stage x^T tile (64j x 128h) as bf16, XOR-swizzled ----
  {
    int hp = tid >> 4;        // h-group: h0 = hp*8
    int jq = tid & 15;        // j-group: j  = jq*4 + jj
    int h0 = hp << 3;
    f32x4 r[8];
    #pragma unroll
    for (int rr = 0; rr < 8; rr++)
      r[rr] = *reinterpret_cast<const f32x4*>(&inb[(size_t)(h0 + rr) * L_ + (jq << 2)]);
    #pragma unroll
    for (int jj = 0; jj < 4; jj++) {
      int j = (jq << 2) + jj;
      uint4 pk;
      pk.x = f2bf(r[0][jj]) | (f2bf(r[1][jj]) << 16);
      pk.y = f2bf(r[2][jj]) | (f2bf(r[3][jj]) << 16);
      pk.z = f2bf(r[4][jj]) | (f2bf(r[5][jj]) << 16);
      pk.w = f2bf(r[6][jj]) | (f2bf(r[7][jj]) << 16);
      int addr = j * 256 + ((hp << 4) ^ ((j & 15) << 4));
      *reinterpret_cast<uint4*>(xb + addr) = pk;
    }
  }
  __syncthreads();

  // ---- MFMA compute: wave tile 64g x 32j ----
  int lane = tid & 63;
  int w    = tid >> 6;
  int wg   = w >> 1;          // g half
  int wj   = w & 1;           // j half
  int ln   = lane & 15;
  int q    = lane >> 4;
  f32x4 acc[4][2];
  #pragma unroll
  for (int mi = 0; mi < 4; mi++)
    #pragma unroll
    for (int n = 0; n < 2; n++) acc[mi][n] = (f32x4)0.0f;

  #pragma unroll
  for (int kb = 0; kb < 4; kb++) {
    bf16x8 a[4], bv[2];
    #pragma unroll
    for (int mi = 0; mi < 4; mi++)
      a[mi] = *reinterpret_cast<const bf16x8*>(
          &w16[(size_t)(wg * 64 + mi * 16 + ln) * 128 + kb * 32 + q * 8]);
    #pragma unroll
    for (int n = 0; n < 2; n++) {
      int jl = wj * 32 + n * 16 + ln;
      int ar = jl * 256 + (((kb << 6) + (q << 4)) ^ ((jl & 15) << 4));
      bv[n] = *reinterpret_cast<bf16x8*>(xb + ar);
    }
    #pragma unroll
    for (int mi = 0; mi < 4; mi++)
      #pragma unroll
      for (int n = 0; n < 2; n++)
        acc[mi][n] = __builtin_amdgcn_mfma_f32_16x16x32_bf16(a[mi], bv[n], acc[mi][n], 0, 0, 0);
  }

  // ---- epilogue ----
  float pa = (MODE == 0) ? prelu_a[0] : 0.0f;
  #pragma unroll
  for (int mi = 0; mi < 4; mi++) {
    #pragma unroll
    for (int r = 0; r < 4; r++) {
      int g = wg * 64 + mi * 16 + q * 4 + r;
      float bvs = bias[g];
      float v0 = acc[mi][0][r] + bvs;
      float v1 = acc[mi][1][r] + bvs;
      if (MODE == 0) {
        v0 = (v0 > 0.0f) ? v0 : pa * v0;
        v1 = (v1 > 0.0f) ? v1 : pa * v1;
      }
      size_t orow = ((size_t)b * H_ + g) * L_ + jb + wj * 32 + ln;
      out[orow]      = v0;
      out[orow + 16] = v1;
      if (MODE == 1) {
        float s1 = v0 + v1;
        float s2 = v0 * v0 + v1 * v1;
        #pragma unroll
        for (int off = 1; off < 16; off <<= 1) {
          s1 += __shfl_xor(s1, off);
          s2 += __shfl_xor(s2, off);
        }
        if (ln == 0) {
          atomicAdd(&bs1[g], s1);
          atomicAdd(&bs2[g], s2);
        }
      }
    }
  }
  if (MODE == 1) {
    __syncthreads();
    if (tid < 128) {
      atomicAdd(&bnsum[tid], bs1[tid]);
      atomicAdd(&bnsumsq[tid], bs2[tid]);
    }
  }
}

// ---------------------------------------------------------------------------
// Chunked SSM scan, in-place u -> y (verified round 1).
// ---------------------------------------------------------------------------
__global__ __launch_bounds__(256) void scan_kernel(
    float* u, const float* __restrict__ consts, const float* __restrict__ Dp)
{
  __shared__ float slds[NCH_][34];
  int c   = threadIdx.x;
  int row = blockIdx.x;
  int h   = row & 127;
  const float* cb = consts + h * 96;
  float wre[16], wim[16];
  #pragma unroll
  for (int n = 0; n < 16; n++) { wre[n] = cb[n]; wim[n] = cb[16 + n]; }

  float* up = u + ((size_t)row << 14) + c * CHUNK_;
  float sre[16], sim[16];
  #pragma unroll
  for (int n = 0; n < 16; n++) { sre[n] = 0.0f; sim[n] = 0.0f; }

  float4 uv = *reinterpret_cast<float4*>(&up[0]);
  for (int q = 0; q < 16; q++) {
    float4 nxt = uv;
    if (q < 15) nxt = *reinterpret_cast<float4*>(&up[(q + 1) * 4]);
    float uu[4] = {uv.x, uv.y, uv.z, uv.w};
    #pragma unroll
    for (int k = 0; k < 4; k++) {
      float uval = uu[k];
      #pragma unroll
      for (int n = 0; n < 16; n++) {
        float nr = fmaf(wre[n], sre[n], fmaf(-wim[n], sim[n], uval));
        float ni = fmaf(wre[n], sim[n], wim[n] * sre[n]);
        sre[n] = nr; sim[n] = ni;
      }
    }
    uv = nxt;
  }
  #pragma unroll
  for (int n = 0; n < 16; n++) { slds[c][2 * n] = sre[n]; slds[c][2 * n + 1] = sim[n]; }
  __syncthreads();

  if (c < 16) {
    int n = c;
    float wcr = cb[64 + n], wci = cb[80 + n];
    float car = 0.0f, cai = 0.0f;
    for (int cc = 0; cc < NCH_; cc++) {
      float lr = slds[cc][2 * n], li = slds[cc][2 * n + 1];
      slds[cc][2 * n] = car; slds[cc][2 * n + 1] = cai;
      float nr = fmaf(wcr, car, fmaf(-wci, cai, lr));
      float ni = fmaf(wcr, cai, fmaf(wci, car, li));
      car = nr; cai = ni;
    }
  }
  __syncthreads();

  float cre[16], cim[16];
  #pragma unroll
  for (int n = 0; n < 16; n++) { cre[n] = cb[32 + n]; cim[n] = cb[48 + n]; }
  float Dv = Dp[h];
  #pragma unroll
  for (int n = 0; n < 16; n++) { sre[n] = slds[c][2 * n]; sim[n] = slds[c][2 * n + 1]; }

  uv = *reinterpret_cast<float4*>(&up[0]);
  for (int q = 0; q < 16; q++) {
    float4 nxt = uv;
    if (q < 15) nxt = *reinterpret_cast<float4*>(&up[(q + 1) * 4]);
    float uu[4] = {uv.x, uv.y, uv.z, uv.w};
    float yy[4];
    #pragma unroll
    for (int k = 0; k < 4; k++) {
      float uval = uu[k];
      float ya = 0.0f;
      #pragma unroll
      for (int n = 0; n < 16; n++) {
        float nr = fmaf(wre[n], sre[n], fmaf(-wim[n], sim[n], uval));
        float ni = fmaf(wre[n], sim[n], wim[n] * sre[n]);
        sre[n] = nr; sim[n] = ni;
        ya = fmaf(cre[n], nr, fmaf(-cim[n], ni, ya));
      }
      yy[k] = fmaf(Dv, uval, 2.0f * ya);
    }
    *reinterpret_cast<float4*>(&up[q * 4]) = make_float4(yy[0], yy[1], yy[2], yy[3]);
    uv = nxt;
  }
}

// ---------------------------------------------------------------------------
__global__ void bnfinal_kernel(const float* __restrict__ bnsum,
                               const float* __restrict__ bnsumsq,
                               float* __restrict__ meanp, float* __restrict__ invp)
{
  int g = threadIdx.x;
  if (g < H_) {
    double cnt = (double)B_ * (double)L_;
    double mu  = (double)bnsum[g] / cnt;
    double var = (double)bnsumsq[g] / cnt - mu * mu;
    meanp[g] = (float)mu;
    invp[g]  = (float)(1.0 / sqrt(var + 1e-5));
  }
}

// ---------------------------------------------------------------------------
// final: BN normalize + FiLM + prelu2 + residual, elementwise, in place
// ---------------------------------------------------------------------------
__global__ __launch_bounds__(256) void final_kernel(
    float* zio, const float* __restrict__ x,
    const float* __restrict__ meanp, const float* __restrict__ invp,
    const float* __restrict__ gact, const float* __restrict__ bact,
    const float* __restrict__ prelu2_a, const float* __restrict__ res_w)
{
  size_t i4 = (size_t)blockIdx.x * 256 + threadIdx.x;
  size_t e  = i4 * 4;
  int bg = (int)(e >> 14);
  int g  = bg & 127;
  float m  = meanp[g], iv = invp[g];
  float ga = gact[bg], bb = bact[bg];
  float rw = res_w[g], pa = prelu2_a[0];
  float4 zv = *reinterpret_cast<float4*>(&zio[e]);
  const float4 xv = *reinterpret_cast<const float4*>(&x[e]);
  float zz[4] = {zv.x, zv.y, zv.z, zv.w};
  float xx[4] = {xv.x, xv.y, xv.z, xv.w};
  #pragma unroll
  for (int k = 0; k < 4; k++) {
    float v = fmaf((zz[k] - m) * iv, ga, bb);
    v = (v > 0.0f) ? v : pa * v;
    zz[k] = fmaf(rw, xx[k], v);
  }
  *reinterpret_cast<float4*>(&zio[e]) = make_float4(zz[0], zz[1], zz[2], zz[3]);
}

// ---------------------------------------------------------------------------
extern "C" void kernel_launch(void* const* d_in, const int* in_sizes, int n_in,
                              void* d_out, int out_size, void* d_ws, size_t ws_size,
                              hipStream_t stream)
{
  const float* x        = (const float*)d_in[0];
  const float* cond     = (const float*)d_in[1];
  const float* lin_w    = (const float*)d_in[2];
  const float* lin_b    = (const float*)d_in[3];
  const float* prelu1_a = (const float*)d_in[4];
  const float* log_dt   = (const float*)d_in[5];
  const float* log_A    = (const float*)d_in[6];
  const float* A_imag   = (const float*)d_in[7];
  const float* C_re     = (const float*)d_in[8];
  const float* C_im     = (const float*)d_in[9];
  const float* Dp       = (const float*)d_in[10];
  const float* out_w    = (const float*)d_in[11];
  const float* out_b    = (const float*)d_in[12];
  const float* film_w   = (const float*)d_in[13];
  const float* film_b   = (const float*)d_in[14];
  const float* prelu2_a = (const float*)d_in[15];
  const float* res_w    = (const float*)d_in[16];
  float* out = (float*)d_out;

  // ws layout (total ~125 KB, well under the 191 KB proven in round 1)
  char* wsb = (char*)d_ws;
  float* bnsum          = (float*)(wsb + 0);       // 128 f32
  float* bnsumsq        = (float*)(wsb + 512);     // 128 f32
  float* consts         = (float*)(wsb + 1024);    // 128*96 f32 = 48 KB
  unsigned short* wA16  = (unsigned short*)(wsb + 50176);  // 32 KB
  unsigned short* wB16  = (unsigned short*)(wsb + 82944);  // 32 KB
  float* gact           = (float*)(wsb + 115712);  // 1024 f32
  float* bact           = (float*)(wsb + 119808);  // 1024 f32
  float* meanp          = (float*)(wsb + 123904);  // 128 f32
  float* invp           = (float*)(wsb + 124416);  // 128 f32

  prep_kernel<<<1, 256, 0, stream>>>(lin_w, out_w, log_dt, log_A, A_imag, C_re, C_im,
                                     cond, film_w, film_b, wA16, wB16, consts, gact, bact,
                                     bnsum, bnsumsq);
  // lin + prelu: x -> u (f32, in d_out)
  mgemm_kernel<0><<<NBLK_, 256, 0, stream>>>(x, wA16, lin_b, prelu1_a, out, nullptr, nullptr);
  // SSM conv + D*u: u -> y, in place
  scan_kernel<<<1024, 256, 0, stream>>>(out, consts, Dp);
  // out layer + bias + BN stats: y -> z, in place
  mgemm_kernel<1><<<NBLK_, 256, 0, stream>>>(out, wB16, out_b, nullptr, out, bnsum, bnsumsq);
  bnfinal_kernel<<<1, 128, 0, stream>>>(bnsum, bnsumsq, meanp, invp);
  // BN + FiLM + prelu2 + residual, in place
  final_kernel<<<16384, 256, 0, stream>>>(out, x, meanp, invp, gact, bact, prelu2_a, res_w);
}